// Round 2
// baseline (1916.711 us; speedup 1.0000x reference)
//
#include <hip/hip_runtime.h>

typedef __bf16 bf16;
typedef __bf16 bf16x4 __attribute__((ext_vector_type(4)));
typedef __bf16 bf16x8 __attribute__((ext_vector_type(8)));
typedef float f32x4 __attribute__((ext_vector_type(4)));
typedef unsigned int u32;
typedef unsigned short u16;

#define CL 2048
#define CN 4
#define CE 1024
#define CH 8

// ---------- async global->LDS, 16B per lane ----------
__device__ __forceinline__ void gload16(const bf16* g, bf16x8* l) {
  __builtin_amdgcn_global_load_lds((const __attribute__((address_space(1))) void*)g,
                                   (__attribute__((address_space(3))) void*)l, 16, 0, 0);
}

// ---------- shared 128x128 (BK=32) NT-GEMM mainloop ----------
// A: MxK row-major (stride lda), B: NxK row-major (B^T, stride ldb).
// 256 threads = 4 waves (2x2), each wave 64x64 = 4x4 16x16x32 bf16 fragments.
// LDS [128][32] bf16 per operand, XOR-swizzle on the 16B-chunk index applied
// to the GLOBAL source + the LDS read index (linear global_load_lds dest).
__device__ __forceinline__ void gemm_mainloop(
    const bf16* __restrict__ Abase, const bf16* __restrict__ Bbase,
    int lda, int ldb, int nk, bf16x8* As, bf16x8* Bs, f32x4 (&acc)[4][4])
{
  const int t = threadIdx.x;
  const int lane = t & 63;
  const int wid = t >> 6;
  const int wr = wid >> 1, wc = wid & 1;
  const int ln15 = lane & 15, kg = lane >> 4;

  int idxA[4], idxB[4];
#pragma unroll
  for (int i = 0; i < 4; ++i) {
    int lrow = wr*64 + i*16 + ln15;
    idxA[i] = lrow*4 + (kg ^ ((lrow >> 1) & 3));
    int lcol = wc*64 + i*16 + ln15;
    idxB[i] = lcol*4 + (kg ^ ((lcol >> 1) & 3));
  }
  const int r0 = t >> 2;         const int s0 = (t & 3) ^ ((r0 >> 1) & 3);
  const int r1 = (t + 256) >> 2; const int s1 = ((t + 256) & 3) ^ ((r1 >> 1) & 3);
  const bf16* a0 = Abase + (size_t)r0 * lda + s0 * 8;
  const bf16* a1 = Abase + (size_t)r1 * lda + s1 * 8;
  const bf16* b0 = Bbase + (size_t)r0 * ldb + s0 * 8;
  const bf16* b1 = Bbase + (size_t)r1 * ldb + s1 * 8;

  for (int kt = 0; kt < nk; ++kt) {
    gload16(a0 + kt * 32, &As[t]);
    gload16(a1 + kt * 32, &As[t + 256]);
    gload16(b0 + kt * 32, &Bs[t]);
    gload16(b1 + kt * 32, &Bs[t + 256]);
    __syncthreads();
    bf16x8 av[4], bv[4];
#pragma unroll
    for (int i = 0; i < 4; ++i) { av[i] = As[idxA[i]]; bv[i] = Bs[idxB[i]]; }
#pragma unroll
    for (int i = 0; i < 4; ++i)
#pragma unroll
      for (int j = 0; j < 4; ++j)
        acc[i][j] = __builtin_amdgcn_mfma_f32_16x16x32_bf16(av[i], bv[j], acc[i][j], 0, 0, 0);
    __syncthreads();
  }
}

// ---------- kernels ----------
__global__ void k_cast(const float4* __restrict__ in, bf16x4* __restrict__ out, int n4) {
  int i = blockIdx.x * 256 + threadIdx.x;
  if (i < n4) {
    float4 v = in[i];
    bf16x4 o = {(bf16)v.x, (bf16)v.y, (bf16)v.z, (bf16)v.w};
    out[i] = o;
  }
}

// Per-head QKV projection: [8192,1024] @ Wh[3072,1024]^T -> split q/k/v,
// each laid out [n][L][E] bf16 (n = m & 3, l = m >> 2); Q pre-scaled 1/32.
__global__ __launch_bounds__(256, 2)
void k_qkv(const bf16* __restrict__ xb, const bf16* __restrict__ Whb,
           const float* __restrict__ bqkv3,
           bf16* __restrict__ qb, bf16* __restrict__ kb, bf16* __restrict__ vb)
{
  __shared__ bf16x8 As[512], Bs[512];
  const int bm = blockIdx.x, bn = blockIdx.y;
  f32x4 acc[4][4] = {};
  const bf16* Ab = xb + (size_t)bm * 128 * CE;
  const bf16* Bb = Whb + (size_t)bn * 128 * CE;
  gemm_mainloop(Ab, Bb, CE, CE, CE / 32, As, Bs, acc);

  const int lane = threadIdx.x & 63, wid = threadIdx.x >> 6;
  const int wr = wid >> 1, wc = wid & 1, ln15 = lane & 15, lg = lane >> 4;
  const int f0 = bn * 128;
  bf16* dst; int e0; float scale = 1.0f;
  if (f0 < CE)          { dst = qb; e0 = f0;          scale = 0.03125f; }
  else if (f0 < 2 * CE) { dst = kb; e0 = f0 - CE; }
  else                  { dst = vb; e0 = f0 - 2 * CE; }
#pragma unroll
  for (int i = 0; i < 4; ++i)
#pragma unroll
    for (int r = 0; r < 4; ++r) {
      int m = bm * 128 + wr * 64 + i * 16 + lg * 4 + r;
      int l = m >> 2, n = m & 3;
      size_t rowbase = ((size_t)n * CL + l) * CE;
#pragma unroll
      for (int j = 0; j < 4; ++j) {
        int fo = wc * 64 + j * 16 + ln15;
        float v = acc[i][j][r] + bqkv3[f0 + fo];
        dst[rowbase + e0 + fo] = (bf16)(v * scale);
      }
    }
}

// V transpose per pair: [L][E] -> [E][L]
__global__ void k_transpose(const bf16* __restrict__ v, bf16* __restrict__ vt)
{
  __shared__ u16 s[64][66];
  const bf16* src = v + (size_t)blockIdx.z * CL * CE;
  bf16* dst = vt + (size_t)blockIdx.z * CE * CL;
  const int l0 = blockIdx.x * 64, e0 = blockIdx.y * 64;
  const int t = threadIdx.x;
#pragma unroll
  for (int rr = 0; rr < 2; ++rr) {
    int c = t + rr * 256;
    int row = c >> 3, cb = (c & 7) * 8;
    uint4 d = *(const uint4*)(src + (size_t)(l0 + row) * CE + e0 + cb);
    u32* sp = (u32*)&s[row][cb];
    sp[0] = d.x; sp[1] = d.y; sp[2] = d.z; sp[3] = d.w;
  }
  __syncthreads();
  const int erow = t >> 2, lc = (t & 3) * 16;
  u32 w[8];
#pragma unroll
  for (int q = 0; q < 8; ++q) {
    u16 a = s[lc + 2 * q][erow];
    u16 b = s[lc + 2 * q + 1][erow];
    w[q] = (u32)a | ((u32)b << 16);
  }
  bf16* dp = dst + (size_t)(e0 + erow) * CL + l0 + lc;
  ((uint4*)dp)[0] = make_uint4(w[0], w[1], w[2], w[3]);
  ((uint4*)dp)[1] = make_uint4(w[4], w[5], w[6], w[7]);
}

// S = Q @ K^T per pair (bf16 out); z = pair 0..3
__global__ __launch_bounds__(256, 2)
void k_scores(const bf16* __restrict__ qb, const bf16* __restrict__ kb,
              bf16* __restrict__ S)
{
  __shared__ bf16x8 As[512], Bs[512];
  const int bm = blockIdx.x, bn = blockIdx.y, p = blockIdx.z;
  f32x4 acc[4][4] = {};
  const bf16* Ab = qb + (size_t)p * CL * CE + (size_t)bm * 128 * CE;
  const bf16* Bb = kb + (size_t)p * CL * CE + (size_t)bn * 128 * CE;
  gemm_mainloop(Ab, Bb, CE, CE, CE / 32, As, Bs, acc);

  const int lane = threadIdx.x & 63, wid = threadIdx.x >> 6;
  const int wr = wid >> 1, wc = wid & 1, ln15 = lane & 15, lg = lane >> 4;
  bf16* Sp = S + (size_t)p * CL * CL;
#pragma unroll
  for (int i = 0; i < 4; ++i)
#pragma unroll
    for (int r = 0; r < 4; ++r) {
      int row = bm * 128 + wr * 64 + i * 16 + lg * 4 + r;
#pragma unroll
      for (int j = 0; j < 4; ++j) {
        int col = bn * 128 + wc * 64 + j * 16 + ln15;
        Sp[(size_t)row * CL + col] = (bf16)acc[i][j][r];
      }
    }
}

// row softmax in place, one wave per row of 2048; 8192 rows total
__global__ __launch_bounds__(256)
void k_softmax(bf16* __restrict__ S)
{
  const int wid = threadIdx.x >> 6, lane = threadIdx.x & 63;
  const size_t row = (size_t)blockIdx.x * 4 + wid;
  ushort4* pv = (ushort4*)(S + row * CL);
  ushort4 d[8];
  float v[32];
#pragma unroll
  for (int c = 0; c < 8; ++c) d[c] = pv[c * 64 + lane];
#pragma unroll
  for (int c = 0; c < 8; ++c) {
    v[c*4+0] = __builtin_bit_cast(float, (u32)d[c].x << 16);
    v[c*4+1] = __builtin_bit_cast(float, (u32)d[c].y << 16);
    v[c*4+2] = __builtin_bit_cast(float, (u32)d[c].z << 16);
    v[c*4+3] = __builtin_bit_cast(float, (u32)d[c].w << 16);
  }
  float m = -1e30f;
#pragma unroll
  for (int i = 0; i < 32; ++i) m = fmaxf(m, v[i]);
#pragma unroll
  for (int o = 32; o; o >>= 1) m = fmaxf(m, __shfl_xor(m, o));
  float ssum = 0.f;
#pragma unroll
  for (int i = 0; i < 32; ++i) { v[i] = __expf(v[i] - m); ssum += v[i]; }
#pragma unroll
  for (int o = 32; o; o >>= 1) ssum += __shfl_xor(ssum, o);
  const float inv = 1.0f / ssum;
#pragma unroll
  for (int c = 0; c < 8; ++c) {
    ushort4 o;
    o.x = __builtin_bit_cast(u16, (bf16)(v[c*4+0] * inv));
    o.y = __builtin_bit_cast(u16, (bf16)(v[c*4+1] * inv));
    o.z = __builtin_bit_cast(u16, (bf16)(v[c*4+2] * inv));
    o.w = __builtin_bit_cast(u16, (bf16)(v[c*4+3] * inv));
    pv[c * 64 + lane] = o;
  }
}

// ctx = P @ V per pair; ctx laid out [m=l*4+n][e] (8192x1024), aliases q
__global__ __launch_bounds__(256, 2)
void k_pv(const bf16* __restrict__ S, const bf16* __restrict__ vt,
          bf16* __restrict__ ctx)
{
  __shared__ bf16x8 As[512], Bs[512];
  const int bm = blockIdx.x, bn = blockIdx.y, p = blockIdx.z;
  f32x4 acc[4][4] = {};
  const bf16* Ab = S + (size_t)p * CL * CL + (size_t)bm * 128 * CL;
  const bf16* Bb = vt + (size_t)p * CE * CL + (size_t)bn * 128 * CL;
  gemm_mainloop(Ab, Bb, CL, CL, CL / 32, As, Bs, acc);

  const int lane = threadIdx.x & 63, wid = threadIdx.x >> 6;
  const int wr = wid >> 1, wc = wid & 1, ln15 = lane & 15, lg = lane >> 4;
#pragma unroll
  for (int i = 0; i < 4; ++i)
#pragma unroll
    for (int r = 0; r < 4; ++r) {
      int l = bm * 128 + wr * 64 + i * 16 + lg * 4 + r;
      int m = l * 4 + p;
#pragma unroll
      for (int j = 0; j < 4; ++j) {
        int e = bn * 128 + wc * 64 + j * 16 + ln15;
        ctx[(size_t)m * CE + e] = (bf16)acc[i][j][r];
      }
    }
}

// out[m][f] (+)= ctx @ Wo_h^T + bo_h; init selects write vs accumulate
__global__ __launch_bounds__(256, 2)
void k_outproj(const bf16* __restrict__ ctx, const bf16* __restrict__ Wohb,
               const float* __restrict__ boh, float* __restrict__ out, int init)
{
  __shared__ bf16x8 As[512], Bs[512];
  const int bm = blockIdx.x, bn = blockIdx.y;
  f32x4 acc[4][4] = {};
  const bf16* Ab = ctx + (size_t)bm * 128 * CE;
  const bf16* Bb = Wohb + (size_t)bn * 128 * CE;
  gemm_mainloop(Ab, Bb, CE, CE, CE / 32, As, Bs, acc);

  const int lane = threadIdx.x & 63, wid = threadIdx.x >> 6;
  const int wr = wid >> 1, wc = wid & 1, ln15 = lane & 15, lg = lane >> 4;
#pragma unroll
  for (int i = 0; i < 4; ++i)
#pragma unroll
    for (int r = 0; r < 4; ++r) {
      int m = bm * 128 + wr * 64 + i * 16 + lg * 4 + r;
#pragma unroll
      for (int j = 0; j < 4; ++j) {
        int f = bn * 128 + wc * 64 + j * 16 + ln15;
        size_t idx = (size_t)m * CE + f;
        float prev = init ? 0.0f : out[idx];
        out[idx] = prev + acc[i][j][r] + boh[f];
      }
    }
}

extern "C" void kernel_launch(void* const* d_in, const int* in_sizes, int n_in,
                              void* d_out, int out_size, void* d_ws, size_t ws_size,
                              hipStream_t stream) {
  const float* x    = (const float*)d_in[0];
  const float* Wqkv = (const float*)d_in[1];
  const float* bqkv = (const float*)d_in[2];
  const float* Wo   = (const float*)d_in[3];
  const float* bo   = (const float*)d_in[4];
  float* out = (float*)d_out;

  // workspace layout (bf16 elements), ~104 MB total
  bf16* xb   = (bf16*)d_ws;                      // 8192*1024          ( 8 Me)
  bf16* Whb  = xb   + (size_t)8192 * 1024;       // 3072*1024          ( 3 Me)
  bf16* Wohb = Whb  + (size_t)3072 * 1024;       // 1024*1024          ( 1 Me)
  bf16* qb   = Wohb + (size_t)1024 * 1024;       // 4*2048*1024        ( 8 Me) [ctx aliases]
  bf16* kb   = qb   + (size_t)4 * 2048 * 1024;   // 4*2048*1024        ( 8 Me)
  bf16* Sb   = kb   + (size_t)4 * 2048 * 1024;   // 4*2048*2048        (16 Me) [vb aliases start]
  bf16* vtb  = Sb   + (size_t)4 * 2048 * 2048;   // 4*1024*2048        ( 8 Me)
  bf16* vb   = Sb;   // alias: V consumed by transpose before scores overwrite
  bf16* ctx  = qb;   // alias: PV writes over q after scores consumed it

  const size_t needed = ((size_t)(8 + 3 + 1 + 8 + 8 + 16 + 8) * 1024 * 1024) * sizeof(bf16);
  if (ws_size < needed) return;  // turn a would-be OOB crash into a clean absmax fail

  k_cast<<<dim3(8192), 256, 0, stream>>>((const float4*)x, (bf16x4*)xb, 8192 * 1024 / 4);

  for (int h = 0; h < CH; ++h) {
    k_cast<<<dim3(3072), 256, 0, stream>>>((const float4*)(Wqkv + (size_t)h * 3072 * 1024),
                                           (bf16x4*)Whb, 3072 * 1024 / 4);
    k_cast<<<dim3(1024), 256, 0, stream>>>((const float4*)(Wo + (size_t)h * 1024 * 1024),
                                           (bf16x4*)Wohb, 1024 * 1024 / 4);
    k_qkv<<<dim3(64, 24), 256, 0, stream>>>(xb, Whb, bqkv + (size_t)h * 3 * CE, qb, kb, vb);
    k_transpose<<<dim3(32, 16, 4), 256, 0, stream>>>(vb, vtb);
    k_scores<<<dim3(16, 16, 4), 256, 0, stream>>>(qb, kb, Sb);
    k_softmax<<<dim3(2048), 256, 0, stream>>>(Sb);
    k_pv<<<dim3(16, 8, 4), 256, 0, stream>>>(Sb, vtb, ctx);
    k_outproj<<<dim3(64, 8), 256, 0, stream>>>(ctx, Wohb, bo + (size_t)h * CE, out, h == 0);
  }
}